// Round 3
// baseline (34.010 us; speedup 1.0000x reference)
//
#include <hip/hip_runtime.h>
#include <hip/hip_cooperative_groups.h>

namespace cg = cooperative_groups;

#define NCOLS 1024
#define NROWS 32

// One cooperative node: 32 blocks (one per row, each on its own CU),
// grid-wide sync, then block 0 averages the 32 row values.
__global__ __launch_bounds__(256) void bpmll_coop_kernel(
    const float* __restrict__ c, const int* __restrict__ y,
    float* __restrict__ ws, float* __restrict__ out) {
    const int row = blockIdx.x;
    const int tid = threadIdx.x;
    const int wave = tid >> 6;
    const int lane = tid & 63;

    // c row interleaved [c1_0, s1_0, c1_1, s1_1, ...]; one float4 = 2 columns
    const float4* __restrict__ crow4 =
        reinterpret_cast<const float4*>(c + (size_t)row * 2 * NCOLS);
    const int2* __restrict__ yrow2 =
        reinterpret_cast<const int2*>(y + (size_t)row * NCOLS);

    float sy = 0.f, sA = 0.f, sB = 0.f, sC = 0.f, sD = 0.f;
    #pragma unroll
    for (int k = 0; k < 2; ++k) {
        const int idx = k * 256 + tid;       // 512 float4 per row
        const float4 F = crow4[idx];
        const int2  Y = yrow2[idx];
        {
            const bool yy = (Y.x != 0);
            const float e1 = __expf(yy ? -F.x : F.x);
            const float e2 = __expf(yy ?  F.y : -F.y);
            sy += yy ? 1.f : 0.f;
            sA += yy ? e1 : 0.f;
            sD += yy ? e2 : 0.f;
            sC += yy ? 0.f : e1;
            sB += yy ? 0.f : e2;
        }
        {
            const bool yy = (Y.y != 0);
            const float e1 = __expf(yy ? -F.z : F.z);
            const float e2 = __expf(yy ?  F.w : -F.w);
            sy += yy ? 1.f : 0.f;
            sA += yy ? e1 : 0.f;
            sD += yy ? e2 : 0.f;
            sC += yy ? 0.f : e1;
            sB += yy ? 0.f : e2;
        }
    }
    #pragma unroll
    for (int off = 32; off > 0; off >>= 1) {
        sy += __shfl_xor(sy, off);
        sA += __shfl_xor(sA, off);
        sB += __shfl_xor(sB, off);
        sC += __shfl_xor(sC, off);
        sD += __shfl_xor(sD, off);
    }
    __shared__ float red[4][5];
    if (lane == 0) {
        red[wave][0] = sy; red[wave][1] = sA; red[wave][2] = sB;
        red[wave][3] = sC; red[wave][4] = sD;
    }
    __syncthreads();
    if (tid == 0) {
        float ty = 0.f, tA = 0.f, tB = 0.f, tC = 0.f, tD = 0.f;
        #pragma unroll
        for (int w = 0; w < 4; ++w) {
            ty += red[w][0]; tA += red[w][1]; tB += red[w][2];
            tC += red[w][3]; tD += red[w][4];
        }
        const float yn  = ty;
        const float ybn = (float)NCOLS - ty;
        const float denom = 2.f * yn * ybn + yn * yn + ybn * ybn;
        ws[row] = (tA + tB) * (tC + tD) / denom;
    }

    cg::this_grid().sync();

    if (blockIdx.x == 0 && tid < 64) {
        float v = (tid < NROWS) ? ws[tid] : 0.f;
        #pragma unroll
        for (int off = 32; off > 0; off >>= 1) v += __shfl_xor(v, off);
        if (tid == 0) out[0] = v * (1.f / NROWS);
    }
}

extern "C" void kernel_launch(void* const* d_in, const int* in_sizes, int n_in,
                              void* d_out, int out_size, void* d_ws, size_t ws_size,
                              hipStream_t stream) {
    const float* c = (const float*)d_in[0];
    const int*   y = (const int*)d_in[1];
    float* out = (float*)d_out;
    float* ws  = (float*)d_ws;
    void* args[] = {(void*)&c, (void*)&y, (void*)&ws, (void*)&out};
    hipLaunchCooperativeKernel((void*)bpmll_coop_kernel,
                               dim3(NROWS), dim3(256), args, 0, stream);
}

// Round 4
// 9.672 us; speedup vs baseline: 3.5165x; 3.5165x over previous
//
#include <hip/hip_runtime.h>

#define NCOLS 1024
#define NROWS 32
#define MAGIC 0x5AC0FFEEu

// One plain node: 32 blocks (one row each). Each block release-stores its row
// value + flag to ws; block 0 acquire-spins on the 31 flags, reduces, writes
// out, then resets flags to 0 (self-restoring -> deterministic per replay).
__global__ __launch_bounds__(256) void bpmll_flag_kernel(
    const float* __restrict__ c, const int* __restrict__ y,
    float* __restrict__ ws, float* __restrict__ out) {
    const int row = blockIdx.x;
    const int tid = threadIdx.x;
    const int wave = tid >> 6;
    const int lane = tid & 63;

    float* vals = ws;                                   // [0..31] row values
    unsigned int* flags = (unsigned int*)(ws + NROWS);  // [0..31] flags

    // c row interleaved [c1_0, s1_0, c1_1, s1_1, ...]; one float4 = 2 columns
    const float4* __restrict__ crow4 =
        reinterpret_cast<const float4*>(c + (size_t)row * 2 * NCOLS);
    const int2* __restrict__ yrow2 =
        reinterpret_cast<const int2*>(y + (size_t)row * NCOLS);

    float sy = 0.f, sA = 0.f, sB = 0.f, sC = 0.f, sD = 0.f;
    #pragma unroll
    for (int k = 0; k < 2; ++k) {
        const int idx = k * 256 + tid;       // 512 float4 per row
        const float4 F = crow4[idx];
        const int2  Y = yrow2[idx];
        {
            const bool yy = (Y.x != 0);
            const float e1 = __expf(yy ? -F.x : F.x);   // exp(∓c1)
            const float e2 = __expf(yy ?  F.y : -F.y);  // exp(±s1)
            sy += yy ? 1.f : 0.f;
            sA += yy ? e1 : 0.f;
            sD += yy ? e2 : 0.f;
            sC += yy ? 0.f : e1;
            sB += yy ? 0.f : e2;
        }
        {
            const bool yy = (Y.y != 0);
            const float e1 = __expf(yy ? -F.z : F.z);
            const float e2 = __expf(yy ?  F.w : -F.w);
            sy += yy ? 1.f : 0.f;
            sA += yy ? e1 : 0.f;
            sD += yy ? e2 : 0.f;
            sC += yy ? 0.f : e1;
            sB += yy ? 0.f : e2;
        }
    }
    #pragma unroll
    for (int off = 32; off > 0; off >>= 1) {
        sy += __shfl_xor(sy, off);
        sA += __shfl_xor(sA, off);
        sB += __shfl_xor(sB, off);
        sC += __shfl_xor(sC, off);
        sD += __shfl_xor(sD, off);
    }
    __shared__ float red[4][5];
    __shared__ float row0val;
    if (lane == 0) {
        red[wave][0] = sy; red[wave][1] = sA; red[wave][2] = sB;
        red[wave][3] = sC; red[wave][4] = sD;
    }
    __syncthreads();
    if (tid == 0) {
        float ty = 0.f, tA = 0.f, tB = 0.f, tC = 0.f, tD = 0.f;
        #pragma unroll
        for (int w = 0; w < 4; ++w) {
            ty += red[w][0]; tA += red[w][1]; tB += red[w][2];
            tC += red[w][3]; tD += red[w][4];
        }
        const float yn  = ty;
        const float ybn = (float)NCOLS - ty;
        const float denom = 2.f * yn * ybn + yn * yn + ybn * ybn;
        const float v = (tA + tB) * (tC + tD) / denom;
        if (row == 0) {
            row0val = v;
        } else {
            __hip_atomic_store(&vals[row], v, __ATOMIC_RELAXED,
                               __HIP_MEMORY_SCOPE_AGENT);
            __hip_atomic_store(&flags[row], MAGIC, __ATOMIC_RELEASE,
                               __HIP_MEMORY_SCOPE_AGENT);
        }
    }
    if (row == 0) {
        __syncthreads();
        if (tid < 64) {
            float v = 0.f;
            if (lane == 0) {
                v = row0val;
            } else if (lane < NROWS) {
                while (__hip_atomic_load(&flags[lane], __ATOMIC_ACQUIRE,
                                         __HIP_MEMORY_SCOPE_AGENT) != MAGIC) {
                    __builtin_amdgcn_s_sleep(1);
                }
                v = __hip_atomic_load(&vals[lane], __ATOMIC_RELAXED,
                                      __HIP_MEMORY_SCOPE_AGENT);
                // reset for next replay (self-restoring state)
                __hip_atomic_store(&flags[lane], 0u, __ATOMIC_RELAXED,
                                   __HIP_MEMORY_SCOPE_AGENT);
            }
            #pragma unroll
            for (int off = 32; off > 0; off >>= 1) v += __shfl_xor(v, off);
            if (lane == 0) out[0] = v * (1.f / NROWS);
        }
    }
}

extern "C" void kernel_launch(void* const* d_in, const int* in_sizes, int n_in,
                              void* d_out, int out_size, void* d_ws, size_t ws_size,
                              hipStream_t stream) {
    const float* c = (const float*)d_in[0];
    const int*   y = (const int*)d_in[1];
    float* out = (float*)d_out;
    float* ws  = (float*)d_ws;
    bpmll_flag_kernel<<<NROWS, 256, 0, stream>>>(c, y, ws, out);
}